// Round 1
// baseline (6576.653 us; speedup 1.0000x reference)
//
#include <hip/hip_runtime.h>

#define Bn  16
#define Ln  256
#define D0n 64
#define Hn  128
#define H4n 512
#define Kn  512
#define BLn 4096   // Bn*Ln

__device__ __forceinline__ float sigf(float x) { return 1.0f / (1.0f + expf(-x)); }

__device__ __forceinline__ float dot4g(const float4* __restrict__ a,
                                       const float4* __restrict__ w, int n4) {
    float acc = 0.f;
    for (int i = 0; i < n4; ++i) {
        float4 x = a[i], y = w[i];
        acc = fmaf(x.x, y.x, acc);
        acc = fmaf(x.y, y.y, acc);
        acc = fmaf(x.z, y.z, acc);
        acc = fmaf(x.w, y.w, acc);
    }
    return acc;
}

// -------- generic row-major Linear: Y[r][c] = X[r][:] . W[c][:] + b[c] --------
__global__ void k_lin(const float* __restrict__ X, const float* __restrict__ W,
                      const float* __restrict__ b, float* __restrict__ Y,
                      int rows, int in_dim, int out_dim, int do_relu) {
    int idx = blockIdx.x * blockDim.x + threadIdx.x;
    if (idx >= rows * out_dim) return;
    int r = idx / out_dim, c = idx % out_dim;
    const float4* x4 = (const float4*)(X + (size_t)r * in_dim);
    const float4* w4 = (const float4*)(W + (size_t)c * in_dim);
    float acc = b[c] + dot4g(x4, w4, in_dim >> 2);
    if (do_relu) acc = fmaxf(acc, 0.f);
    Y[idx] = acc;
}

// -------- enc_lin2 with concatenated [hf, hb] input --------
__global__ void k_enc_lin2(const float* __restrict__ hf, const float* __restrict__ hb,
                           const float* __restrict__ W2, const float* __restrict__ b2,
                           float* __restrict__ ze) {
    int idx = blockIdx.x * blockDim.x + threadIdx.x;
    if (idx >= BLn * Hn) return;
    int r = idx / Hn, c = idx % Hn;
    const float* w = W2 + (size_t)c * (2 * Hn);
    float acc = b2[c];
    acc += dot4g((const float4*)(hf + (size_t)r * Hn), (const float4*)w, Hn >> 2);
    acc += dot4g((const float4*)(hb + (size_t)r * Hn), (const float4*)(w + Hn), Hn >> 2);
    ze[idx] = acc;
}

// -------- LSTM scan (both directions in one launch; block = dir*16 + batch) ----
// xW* holds precomputed x @ Wih^T + b  (B, L, 4H)
__global__ __launch_bounds__(512)
void k_lstm_scan(const float* __restrict__ xWf, const float* __restrict__ xWb,
                 const float* __restrict__ Whh_f, const float* __restrict__ Whh_b,
                 float* __restrict__ hf, float* __restrict__ hb) {
    const int b   = blockIdx.x & 15;
    const int rev = blockIdx.x >> 4;
    const int tid = threadIdx.x;            // 0..511 -> gate row j
    const float* xW  = rev ? xWb : xWf;
    const float* Whh = rev ? Whh_b : Whh_f;
    float*       ho  = rev ? hb  : hf;

    __shared__ __align__(16) float h_s[Hn];
    __shared__ __align__(16) float g_s[H4n];

    float c_reg = 0.f;
    if (tid < Hn) h_s[tid] = 0.f;

    // keep this thread's Whh row resident in registers (reused 256x)
    float4 wh[32];
    {
        const float4* p = (const float4*)(Whh + (size_t)tid * Hn);
#pragma unroll
        for (int i = 0; i < 32; ++i) wh[i] = p[i];
    }
    __syncthreads();

    for (int s = 0; s < Ln; ++s) {
        const int t = rev ? (Ln - 1 - s) : s;
        const float* xw = xW + ((size_t)b * Ln + t) * H4n;
        float acc = xw[tid];
        const float4* h4 = (const float4*)h_s;
#pragma unroll
        for (int i = 0; i < 32; ++i) {
            float4 hv = h4[i];
            acc = fmaf(hv.x, wh[i].x, acc);
            acc = fmaf(hv.y, wh[i].y, acc);
            acc = fmaf(hv.z, wh[i].z, acc);
            acc = fmaf(hv.w, wh[i].w, acc);
        }
        g_s[tid] = acc;
        __syncthreads();
        if (tid < Hn) {
            float ig = sigf(g_s[tid]);
            float fg = sigf(g_s[Hn + tid]);
            float gg = tanhf(g_s[2 * Hn + tid]);
            float og = sigf(g_s[3 * Hn + tid]);
            c_reg = fg * c_reg + ig * gg;
            float hv = og * tanhf(c_reg);
            h_s[tid] = hv;
            ho[((size_t)b * Ln + t) * Hn + tid] = hv;
        }
        __syncthreads();
    }
}

// -------- codebook squared norms --------
__global__ void k_codenorm(const float* __restrict__ emb, float* __restrict__ c2) {
    int k = blockIdx.x * blockDim.x + threadIdx.x;
    if (k >= Kn) return;
    const float4* e4 = (const float4*)(emb + (size_t)k * Hn);
    float acc = 0.f;
    for (int i = 0; i < Hn / 4; ++i) {
        float4 v = e4[i];
        acc = fmaf(v.x, v.x, acc); acc = fmaf(v.y, v.y, acc);
        acc = fmaf(v.z, v.z, acc); acc = fmaf(v.w, v.w, acc);
    }
    c2[k] = acc;
}

// -------- VQ: argmin_k (||e_k||^2 - 2 ze.e_k), first-index tie-break; zq = emb[k*] --
__global__ __launch_bounds__(256)
void k_vq(const float* __restrict__ ze, const float* __restrict__ emb,
          const float* __restrict__ c2, float* __restrict__ zq) {
    const int p = blockIdx.x;           // b*L + l
    const int tid = threadIdx.x;        // 256
    __shared__ __align__(16) float z_s[Hn];
    __shared__ float vals[256];
    __shared__ int   idxs[256];
    if (tid < Hn) z_s[tid] = ze[(size_t)p * Hn + tid];
    __syncthreads();

    float best = 3.0e38f; int bidx = 0;
    for (int k = tid; k < Kn; k += 256) {
        float d = c2[k] - 2.f * dot4g((const float4*)z_s,
                                      (const float4*)(emb + (size_t)k * Hn), Hn >> 2);
        if (d < best) { best = d; bidx = k; }   // strict <  => first occurrence
    }
    vals[tid] = best; idxs[tid] = bidx;
    __syncthreads();
    for (int s = 128; s > 0; s >>= 1) {
        if (tid < s) {
            float v2 = vals[tid + s]; int i2 = idxs[tid + s];
            if (v2 < vals[tid] || (v2 == vals[tid] && i2 < idxs[tid])) {
                vals[tid] = v2; idxs[tid] = i2;
            }
        }
        __syncthreads();
    }
    const int nearest = idxs[0];
    if (tid < Hn) zq[(size_t)p * Hn + tid] = emb[(size_t)nearest * Hn + tid];
}

// -------- autoregressive decoder: one block per batch --------
__global__ __launch_bounds__(512)
void k_decoder(const float* __restrict__ kp, const float* __restrict__ vp,
               const float* __restrict__ mask,
               const float* __restrict__ W1,  const float* __restrict__ b1,
               const float* __restrict__ Wih, const float* __restrict__ Whh,
               const float* __restrict__ bd,
               const float* __restrict__ Wq,  const float* __restrict__ bq,
               const float* __restrict__ W2,  const float* __restrict__ b2,
               float* __restrict__ dec_out, float* __restrict__ attn_w) {
    const int b    = blockIdx.x;
    const int tid  = threadIdx.x;
    const int lane = tid & 63;
    const int wid  = tid >> 6;

    __shared__ __align__(16) float tok_s[D0n];
    __shared__ __align__(16) float x_s[Hn];
    __shared__ __align__(16) float h_s[Hn];
    __shared__ __align__(16) float q_s[Hn];
    __shared__ __align__(16) float g_s[H4n];
    __shared__ __align__(16) float attn_s[Ln];
    __shared__ __align__(16) float ctxp[4][Hn];
    __shared__ __align__(16) float ctx_s[Hn];
    __shared__ float red_s[8];

    float c_reg = 0.f;
    if (tid < D0n) tok_s[tid] = 0.f;
    if (tid < Hn)  h_s[tid]   = 0.f;

    // resident Whh row (reused 256x)
    float4 wh[32];
    {
        const float4* p = (const float4*)(Whh + (size_t)tid * Hn);
#pragma unroll
        for (int i = 0; i < 32; ++i) wh[i] = p[i];
    }
    const float* kpb = kp + (size_t)b * Ln * Hn;
    const float* vpb = vp + (size_t)b * Ln * Hn;
    const float scale = 0.088388347648318447f;   // 1/sqrt(128)
    float madd = 0.f;
    if (tid < Ln) madd = (mask[(size_t)b * Ln + tid] == 0.f) ? -1e9f : 0.f;
    __syncthreads();

    for (int t = 0; t < Ln; ++t) {
        // x = relu(tok @ W1^T + b1)
        if (tid < Hn) {
            float acc = b1[tid] + dot4g((const float4*)tok_s,
                                        (const float4*)(W1 + (size_t)tid * D0n), D0n >> 2);
            x_s[tid] = fmaxf(acc, 0.f);
        }
        __syncthreads();
        // g = bd + Wih@x + Whh@h   (h is previous step's)
        {
            const float4* wi = (const float4*)(Wih + (size_t)tid * Hn);
            const float4* x4 = (const float4*)x_s;
            const float4* h4 = (const float4*)h_s;
            float acc = bd[tid];
#pragma unroll
            for (int i = 0; i < 32; ++i) {
                float4 xv = x4[i], wv = wi[i];
                acc = fmaf(xv.x, wv.x, acc); acc = fmaf(xv.y, wv.y, acc);
                acc = fmaf(xv.z, wv.z, acc); acc = fmaf(xv.w, wv.w, acc);
                float4 hv = h4[i];
                acc = fmaf(hv.x, wh[i].x, acc); acc = fmaf(hv.y, wh[i].y, acc);
                acc = fmaf(hv.z, wh[i].z, acc); acc = fmaf(hv.w, wh[i].w, acc);
            }
            g_s[tid] = acc;
        }
        __syncthreads();
        if (tid < Hn) {
            float ig = sigf(g_s[tid]);
            float fg = sigf(g_s[Hn + tid]);
            float gg = tanhf(g_s[2 * Hn + tid]);
            float og = sigf(g_s[3 * Hn + tid]);
            c_reg = fg * c_reg + ig * gg;
            h_s[tid] = og * tanhf(c_reg);
        }
        __syncthreads();
        if (tid < Hn) {
            q_s[tid] = bq[tid] + dot4g((const float4*)h_s,
                                       (const float4*)(Wq + (size_t)tid * Hn), Hn >> 2);
        }
        __syncthreads();
        // scores + softmax over L (threads 0..255 hold one l each)
        float sv = -1e30f;
        if (tid < Ln) {
            float acc = dot4g((const float4*)q_s,
                              (const float4*)(kpb + (size_t)tid * Hn), Hn >> 2);
            sv = acc * scale + madd;
        }
        float m = sv;
#pragma unroll
        for (int o = 32; o > 0; o >>= 1) m = fmaxf(m, __shfl_xor(m, o, 64));
        if (lane == 0) red_s[wid] = m;
        __syncthreads();
        m = fmaxf(fmaxf(red_s[0], red_s[1]), fmaxf(red_s[2], red_s[3]));
        float e = (tid < Ln) ? expf(sv - m) : 0.f;
        float sum = e;
#pragma unroll
        for (int o = 32; o > 0; o >>= 1) sum += __shfl_xor(sum, o, 64);
        __syncthreads();            // everyone done reading red_s (max) before reuse
        if (lane == 0) red_s[wid] = sum;
        __syncthreads();
        float tot = red_s[0] + red_s[1] + red_s[2] + red_s[3];
        float pa = e / tot;
        if (tid < Ln) {
            attn_s[tid] = pa;
            attn_w[((size_t)b * Ln + t) * Ln + tid] = pa;
        }
        __syncthreads();
        // ctx[d] = sum_l attn[l] * v[l][d] — 4 partial slabs of 64 l each
        {
            int part = tid >> 7;        // 0..3
            int d    = tid & 127;
            float acc = 0.f;
            int l0 = part * 64;
            for (int l = l0; l < l0 + 64; ++l)
                acc = fmaf(attn_s[l], vpb[(size_t)l * Hn + d], acc);
            ctxp[part][d] = acc;
        }
        __syncthreads();
        if (tid < Hn) ctx_s[tid] = ctxp[0][tid] + ctxp[1][tid] + ctxp[2][tid] + ctxp[3][tid];
        __syncthreads();
        if (tid < D0n) {
            float acc = b2[tid] + dot4g((const float4*)ctx_s,
                                        (const float4*)(W2 + (size_t)tid * Hn), Hn >> 2);
            tok_s[tid] = acc;
            dec_out[((size_t)b * Ln + t) * D0n + tid] = acc;
        }
        __syncthreads();
    }
}

extern "C" void kernel_launch(void* const* d_in, const int* in_sizes, int n_in,
                              void* d_out, int out_size, void* d_ws, size_t ws_size,
                              hipStream_t stream) {
    const float* inputs     = (const float*)d_in[0];
    // d_in[1] = input_lens (int64) — unused by the forward pass
    const float* in_mask    = (const float*)d_in[2];
    const float* enc_lin1_W = (const float*)d_in[3];
    const float* enc_lin1_b = (const float*)d_in[4];
    const float* enc_Wih_f  = (const float*)d_in[5];
    const float* enc_Whh_f  = (const float*)d_in[6];
    const float* enc_b_f    = (const float*)d_in[7];
    const float* enc_Wih_b  = (const float*)d_in[8];
    const float* enc_Whh_b  = (const float*)d_in[9];
    const float* enc_b_b    = (const float*)d_in[10];
    const float* enc_lin2_W = (const float*)d_in[11];
    const float* enc_lin2_b = (const float*)d_in[12];
    const float* vq_emb     = (const float*)d_in[13];
    const float* dec_lin1_W = (const float*)d_in[14];
    const float* dec_lin1_b = (const float*)d_in[15];
    const float* dec_Wih    = (const float*)d_in[16];
    const float* dec_Whh    = (const float*)d_in[17];
    const float* dec_b     = (const float*)d_in[18];
    const float* attn_Wq    = (const float*)d_in[19];
    const float* attn_bq    = (const float*)d_in[20];
    const float* attn_Wk    = (const float*)d_in[21];
    const float* attn_bk    = (const float*)d_in[22];
    const float* attn_Wv    = (const float*)d_in[23];
    const float* attn_bv    = (const float*)d_in[24];
    const float* dec_lin2_W = (const float*)d_in[25];
    const float* dec_lin2_b = (const float*)d_in[26];

    float* out     = (float*)d_out;
    float* dec_out = out;                       // 16*256*64   = 262144
    float* attn_w  = out + 262144;              // 16*256*256  = 1048576
    float* ze      = out + 1310720;             // 16*256*128  = 524288
    float* zq      = out + 1835008;             // 16*256*128  = 524288

    float* ws    = (float*)d_ws;
    float* enc_x = ws;                          // 524288
    float* xWf   = enc_x + 524288;              // 2097152
    float* xWb   = xWf + 2097152;               // 2097152
    float* hf    = xWb + 2097152;               // 524288
    float* hb    = hf + 524288;                 // 524288
    float* kp    = hb + 524288;                 // 524288
    float* vp    = kp + 524288;                 // 524288
    float* c2    = vp + 524288;                 // 512

    // 1. enc_x = relu(inputs @ W1^T + b1)
    k_lin<<<(BLn * Hn + 255) / 256, 256, 0, stream>>>(
        inputs, enc_lin1_W, enc_lin1_b, enc_x, BLn, D0n, Hn, 1);
    // 2. hoisted x @ Wih^T + b for both directions (no h-dependency)
    k_lin<<<(BLn * H4n + 255) / 256, 256, 0, stream>>>(
        enc_x, enc_Wih_f, enc_b_f, xWf, BLn, Hn, H4n, 0);
    k_lin<<<(BLn * H4n + 255) / 256, 256, 0, stream>>>(
        enc_x, enc_Wih_b, enc_b_b, xWb, BLn, Hn, H4n, 0);
    // 3. BiLSTM sequential scans (fwd + bwd concurrently, 32 blocks)
    k_lstm_scan<<<32, 512, 0, stream>>>(xWf, xWb, enc_Whh_f, enc_Whh_b, hf, hb);
    // 4. ze = [hf, hb] @ W2^T + b2
    k_enc_lin2<<<(BLn * Hn + 255) / 256, 256, 0, stream>>>(hf, hb, enc_lin2_W, enc_lin2_b, ze);
    // 5. VQ
    k_codenorm<<<2, 256, 0, stream>>>(vq_emb, c2);
    k_vq<<<BLn, 256, 0, stream>>>(ze, vq_emb, c2, zq);
    // 6. attention K/V projections from dec_in (== zq numerically)
    k_lin<<<(BLn * Hn + 255) / 256, 256, 0, stream>>>(zq, attn_Wk, attn_bk, kp, BLn, Hn, Hn, 0);
    k_lin<<<(BLn * Hn + 255) / 256, 256, 0, stream>>>(zq, attn_Wv, attn_bv, vp, BLn, Hn, Hn, 0);
    // 7. autoregressive decoder
    k_decoder<<<Bn, 512, 0, stream>>>(kp, vp, in_mask,
                                      dec_lin1_W, dec_lin1_b,
                                      dec_Wih, dec_Whh, dec_b,
                                      attn_Wq, attn_bq,
                                      dec_lin2_W, dec_lin2_b,
                                      dec_out, attn_w);
}

// Round 2
// 6339.137 us; speedup vs baseline: 1.0375x; 1.0375x over previous
//
#include <hip/hip_runtime.h>

#define Bn  16
#define Ln  256
#define D0n 64
#define Hn  128
#define H4n 512
#define Kn  512
#define BLn 4096   // Bn*Ln

__device__ __forceinline__ float sigf(float x) { return 1.0f / (1.0f + expf(-x)); }

__device__ __forceinline__ float fma4(float4 w, float4 x, float acc) {
    acc = fmaf(w.x, x.x, acc);
    acc = fmaf(w.y, x.y, acc);
    acc = fmaf(w.z, x.z, acc);
    acc = fmaf(w.w, x.w, acc);
    return acc;
}

// ILP-4 dot product (n4 must be a multiple of 4)
__device__ __forceinline__ float dotn(const float4* __restrict__ a,
                                      const float4* __restrict__ w, int n4) {
    float a0 = 0.f, a1 = 0.f, a2 = 0.f, a3 = 0.f;
    for (int i = 0; i < n4; i += 4) {
        a0 = fma4(a[i], w[i], a0);
        a1 = fma4(a[i + 1], w[i + 1], a1);
        a2 = fma4(a[i + 2], w[i + 2], a2);
        a3 = fma4(a[i + 3], w[i + 3], a3);
    }
    return (a0 + a1) + (a2 + a3);
}

// -------- generic row-major Linear: Y[r][c] = X[r][:] . W[c][:] + b[c] --------
__global__ void k_lin(const float* __restrict__ X, const float* __restrict__ W,
                      const float* __restrict__ b, float* __restrict__ Y,
                      int rows, int in_dim, int out_dim, int do_relu) {
    int idx = blockIdx.x * blockDim.x + threadIdx.x;
    if (idx >= rows * out_dim) return;
    int r = idx / out_dim, c = idx % out_dim;
    const float4* x4 = (const float4*)(X + (size_t)r * in_dim);
    const float4* w4 = (const float4*)(W + (size_t)c * in_dim);
    float acc = b[c] + dotn(x4, w4, in_dim >> 2);
    if (do_relu) acc = fmaxf(acc, 0.f);
    Y[idx] = acc;
}

// -------- enc_lin2 with concatenated [hf, hb] input --------
__global__ void k_enc_lin2(const float* __restrict__ hf, const float* __restrict__ hb,
                           const float* __restrict__ W2, const float* __restrict__ b2,
                           float* __restrict__ ze) {
    int idx = blockIdx.x * blockDim.x + threadIdx.x;
    if (idx >= BLn * Hn) return;
    int r = idx / Hn, c = idx % Hn;
    const float* w = W2 + (size_t)c * (2 * Hn);
    float acc = b2[c];
    acc += dotn((const float4*)(hf + (size_t)r * Hn), (const float4*)w, Hn >> 2);
    acc += dotn((const float4*)(hb + (size_t)r * Hn), (const float4*)(w + Hn), Hn >> 2);
    ze[idx] = acc;
}

// -------- LSTM scan: 1024 thr, 2 threads per gate row, half-row Whh resident ----
// xW* holds precomputed x @ Wih^T + b  (B, L, 4H)
__global__ __launch_bounds__(1024)
void k_lstm_scan(const float* __restrict__ xWf, const float* __restrict__ xWb,
                 const float* __restrict__ Whh_f, const float* __restrict__ Whh_b,
                 float* __restrict__ hf, float* __restrict__ hb) {
    const int b   = blockIdx.x & 15;
    const int rev = blockIdx.x >> 4;
    const int tid = threadIdx.x;          // 0..1023
    const int row  = tid >> 1;            // gate row 0..511
    const int half = tid & 1;             // which 64-elem half of h
    const float* xW  = rev ? xWb : xWf;
    const float* Whh = rev ? Whh_b : Whh_f;
    float*       ho  = rev ? hb  : hf;

    __shared__ __align__(16) float h_s[Hn];
    __shared__ __align__(16) float g_s[H4n];

    float c_reg = 0.f;
    if (tid < Hn) h_s[tid] = 0.f;

    // resident HALF-row of Whh: 16 float4 = 64 VGPR (no spill)
    float4 w[16];
    {
        const float4* p = (const float4*)(Whh + (size_t)row * Hn + half * 64);
#pragma unroll
        for (int i = 0; i < 16; ++i) w[i] = p[i];
    }
    __syncthreads();

    for (int s = 0; s < Ln; ++s) {
        const int t = rev ? (Ln - 1 - s) : s;
        const float4* hh = (const float4*)(h_s + half * 64);
        float a0 = 0.f, a1 = 0.f, a2 = 0.f, a3 = 0.f;
#pragma unroll
        for (int i = 0; i < 16; i += 4) {
            a0 = fma4(w[i], hh[i], a0);
            a1 = fma4(w[i + 1], hh[i + 1], a1);
            a2 = fma4(w[i + 2], hh[i + 2], a2);
            a3 = fma4(w[i + 3], hh[i + 3], a3);
        }
        float acc = (a0 + a1) + (a2 + a3);
        acc += __shfl_xor(acc, 1);
        if (half == 0)
            g_s[row] = acc + xW[((size_t)b * Ln + t) * H4n + row];
        __syncthreads();
        if (tid < Hn) {
            float ig = sigf(g_s[tid]);
            float fg = sigf(g_s[Hn + tid]);
            float gg = tanhf(g_s[2 * Hn + tid]);
            float og = sigf(g_s[3 * Hn + tid]);
            c_reg = fg * c_reg + ig * gg;
            float hv = og * tanhf(c_reg);
            h_s[tid] = hv;
            ho[((size_t)b * Ln + t) * Hn + tid] = hv;
        }
        __syncthreads();
    }
}

// -------- codebook squared norms --------
__global__ void k_codenorm(const float* __restrict__ emb, float* __restrict__ c2) {
    int k = blockIdx.x * blockDim.x + threadIdx.x;
    if (k >= Kn) return;
    const float4* e4 = (const float4*)(emb + (size_t)k * Hn);
    float acc = 0.f;
    for (int i = 0; i < Hn / 4; ++i) {
        float4 v = e4[i];
        acc = fmaf(v.x, v.x, acc); acc = fmaf(v.y, v.y, acc);
        acc = fmaf(v.z, v.z, acc); acc = fmaf(v.w, v.w, acc);
    }
    c2[k] = acc;
}

// -------- VQ: argmin_k (||e_k||^2 - 2 ze.e_k), first-index tie-break --------
__global__ __launch_bounds__(256)
void k_vq(const float* __restrict__ ze, const float* __restrict__ emb,
          const float* __restrict__ c2, float* __restrict__ zq) {
    const int p = blockIdx.x;           // b*L + l
    const int tid = threadIdx.x;        // 256
    __shared__ __align__(16) float z_s[Hn];
    __shared__ float vals[256];
    __shared__ int   idxs[256];
    if (tid < Hn) z_s[tid] = ze[(size_t)p * Hn + tid];
    __syncthreads();

    float best = 3.0e38f; int bidx = 0;
    for (int k = tid; k < Kn; k += 256) {
        float d = c2[k] - 2.f * dotn((const float4*)z_s,
                                     (const float4*)(emb + (size_t)k * Hn), Hn >> 2);
        if (d < best) { best = d; bidx = k; }   // strict <  => first occurrence
    }
    vals[tid] = best; idxs[tid] = bidx;
    __syncthreads();
    for (int s = 128; s > 0; s >>= 1) {
        if (tid < s) {
            float v2 = vals[tid + s]; int i2 = idxs[tid + s];
            if (v2 < vals[tid] || (v2 == vals[tid] && i2 < idxs[tid])) {
                vals[tid] = v2; idxs[tid] = i2;
            }
        }
        __syncthreads();
    }
    const int nearest = idxs[0];
    if (tid < Hn) zq[(size_t)p * Hn + tid] = emb[(size_t)nearest * Hn + tid];
}

// -------- autoregressive decoder: one block (1024 thr) per batch --------
// All weights streamed from L2 (shared across blocks, hot). Split-dot phases:
//   x: 128 rows x 8 thr | gates: 512 rows x 2 thr | q: 128 x 8
//   scores: 256 l x 4 thr | softmax: wave 0 only | ctx: 8 slabs x 128 d
//   out: 64 rows x 16 thr (folds ctx-slab combine)
__global__ __launch_bounds__(1024)
void k_decoder(const float* __restrict__ kp, const float* __restrict__ vp,
               const float* __restrict__ mask,
               const float* __restrict__ W1,  const float* __restrict__ b1,
               const float* __restrict__ Wih, const float* __restrict__ Whh,
               const float* __restrict__ bd,
               const float* __restrict__ Wq,  const float* __restrict__ bq,
               const float* __restrict__ W2,  const float* __restrict__ b2,
               float* __restrict__ dec_out, float* __restrict__ attn_w) {
    const int b    = blockIdx.x;
    const int tid  = threadIdx.x;
    const int lane = tid & 63;
    const int wid  = tid >> 6;

    __shared__ __align__(16) float tok_s[D0n];
    __shared__ __align__(16) float x_s[Hn];
    __shared__ __align__(16) float h_s[Hn];
    __shared__ __align__(16) float q_s[Hn];
    __shared__ __align__(16) float g_s[H4n];
    __shared__ __align__(16) float s_s[Ln];
    __shared__ __align__(16) float attn_s[Ln];
    __shared__ __align__(16) float ctxp[8][Hn];
    __shared__ __align__(16) float madd_s[Ln];
    __shared__ __align__(16) float b1_s[Hn];
    __shared__ __align__(16) float bd_s[H4n];
    __shared__ __align__(16) float bq_s[Hn];
    __shared__ __align__(16) float b2_s[D0n];

    float c_reg = 0.f;
    if (tid < D0n) { tok_s[tid] = 0.f; b2_s[tid] = b2[tid]; }
    if (tid < Hn)  { h_s[tid] = 0.f; b1_s[tid] = b1[tid]; bq_s[tid] = bq[tid]; }
    if (tid < H4n) bd_s[tid] = bd[tid];
    if (tid < Ln)  madd_s[tid] = (mask[(size_t)b * Ln + tid] == 0.f) ? -1e9f : 0.f;

    const float* kpb = kp + (size_t)b * Ln * Hn;
    const float* vpb = vp + (size_t)b * Ln * Hn;
    const float scale = 0.088388347648318447f;   // 1/sqrt(128)
    __syncthreads();

    for (int t = 0; t < Ln; ++t) {
        // ---- A: x = relu(W1 @ tok + b1); 128 rows x 8 threads ----
        {
            int row = tid >> 3, part = tid & 7;
            const float4* wv = (const float4*)(W1 + (size_t)row * D0n + part * 8);
            const float4* t4 = (const float4*)(tok_s + part * 8);
            float acc = fma4(wv[0], t4[0], 0.f);
            acc = fma4(wv[1], t4[1], acc);
            acc += __shfl_xor(acc, 1);
            acc += __shfl_xor(acc, 2);
            acc += __shfl_xor(acc, 4);
            if (part == 0) x_s[row] = fmaxf(acc + b1_s[row], 0.f);
        }
        __syncthreads();
        // ---- B: gates = Wih@x + Whh@h + bd; 512 rows x 2 threads ----
        {
            int row = tid >> 1, half = tid & 1;
            const float4* wi = (const float4*)(Wih + (size_t)row * Hn + half * 64);
            const float4* wh = (const float4*)(Whh + (size_t)row * Hn + half * 64);
            const float4* xx = (const float4*)(x_s + half * 64);
            const float4* hh = (const float4*)(h_s + half * 64);
            float a0 = 0.f, a1 = 0.f, a2 = 0.f, a3 = 0.f;
#pragma unroll
            for (int i = 0; i < 16; i += 4) {
                a0 = fma4(wi[i], xx[i], a0);
                a1 = fma4(wi[i + 1], xx[i + 1], a1);
                a2 = fma4(wi[i + 2], xx[i + 2], a2);
                a3 = fma4(wi[i + 3], xx[i + 3], a3);
            }
#pragma unroll
            for (int i = 0; i < 16; i += 4) {
                a0 = fma4(wh[i], hh[i], a0);
                a1 = fma4(wh[i + 1], hh[i + 1], a1);
                a2 = fma4(wh[i + 2], hh[i + 2], a2);
                a3 = fma4(wh[i + 3], hh[i + 3], a3);
            }
            float acc = (a0 + a1) + (a2 + a3);
            acc += __shfl_xor(acc, 1);
            if (half == 0) g_s[row] = acc + bd_s[row];
        }
        __syncthreads();
        // ---- C: LSTM cell (threads 0..127) ----
        if (tid < Hn) {
            float ig = sigf(g_s[tid]);
            float fg = sigf(g_s[Hn + tid]);
            float gg = tanhf(g_s[2 * Hn + tid]);
            float og = sigf(g_s[3 * Hn + tid]);
            c_reg = fg * c_reg + ig * gg;
            h_s[tid] = og * tanhf(c_reg);
        }
        __syncthreads();
        // ---- D: q = Wq@h + bq; 128 rows x 8 threads ----
        {
            int row = tid >> 3, part = tid & 7;
            const float4* wv = (const float4*)(Wq + (size_t)row * Hn + part * 16);
            const float4* hh = (const float4*)(h_s + part * 16);
            float a0 = fma4(wv[0], hh[0], 0.f);
            float a1 = fma4(wv[1], hh[1], 0.f);
            a0 = fma4(wv[2], hh[2], a0);
            a1 = fma4(wv[3], hh[3], a1);
            float acc = a0 + a1;
            acc += __shfl_xor(acc, 1);
            acc += __shfl_xor(acc, 2);
            acc += __shfl_xor(acc, 4);
            if (part == 0) q_s[row] = acc + bq_s[row];
        }
        __syncthreads();
        // ---- E: scores; 256 l x 4 threads ----
        {
            int l = tid >> 2, part = tid & 3;
            const float4* kk = (const float4*)(kpb + (size_t)l * Hn + part * 32);
            const float4* qq = (const float4*)(q_s + part * 32);
            float a0 = 0.f, a1 = 0.f, a2 = 0.f, a3 = 0.f;
            a0 = fma4(kk[0], qq[0], a0); a1 = fma4(kk[1], qq[1], a1);
            a2 = fma4(kk[2], qq[2], a2); a3 = fma4(kk[3], qq[3], a3);
            a0 = fma4(kk[4], qq[4], a0); a1 = fma4(kk[5], qq[5], a1);
            a2 = fma4(kk[6], qq[6], a2); a3 = fma4(kk[7], qq[7], a3);
            float acc = (a0 + a1) + (a2 + a3);
            acc += __shfl_xor(acc, 1);
            acc += __shfl_xor(acc, 2);
            if (part == 0) s_s[l] = acc * scale + madd_s[l];
        }
        __syncthreads();
        // ---- F: softmax, wave 0 only (no internal barriers) ----
        if (wid == 0) {
            float v0 = s_s[lane],        v1 = s_s[lane + 64];
            float v2 = s_s[lane + 128],  v3 = s_s[lane + 192];
            float m = fmaxf(fmaxf(v0, v1), fmaxf(v2, v3));
#pragma unroll
            for (int o = 32; o > 0; o >>= 1) m = fmaxf(m, __shfl_xor(m, o));
            float e0 = expf(v0 - m), e1 = expf(v1 - m);
            float e2 = expf(v2 - m), e3 = expf(v3 - m);
            float s = (e0 + e1) + (e2 + e3);
#pragma unroll
            for (int o = 32; o > 0; o >>= 1) s += __shfl_xor(s, o);
            float inv = 1.f / s;
            e0 *= inv; e1 *= inv; e2 *= inv; e3 *= inv;
            attn_s[lane] = e0; attn_s[lane + 64] = e1;
            attn_s[lane + 128] = e2; attn_s[lane + 192] = e3;
            float* aw = attn_w + ((size_t)b * Ln + t) * Ln;
            aw[lane] = e0; aw[lane + 64] = e1;
            aw[lane + 128] = e2; aw[lane + 192] = e3;
        }
        __syncthreads();
        // ---- G: ctx partials; 8 slabs of 32 l x 128 d ----
        {
            int slab = tid >> 7, d = tid & 127;
            const float* vb = vpb + (size_t)(slab * 32) * Hn + d;
            const float* as = attn_s + slab * 32;
            float a0 = 0.f, a1 = 0.f, a2 = 0.f, a3 = 0.f;
#pragma unroll
            for (int l = 0; l < 32; l += 4) {
                a0 = fmaf(as[l],     vb[(size_t)l * Hn],       a0);
                a1 = fmaf(as[l + 1], vb[(size_t)(l + 1) * Hn], a1);
                a2 = fmaf(as[l + 2], vb[(size_t)(l + 2) * Hn], a2);
                a3 = fmaf(as[l + 3], vb[(size_t)(l + 3) * Hn], a3);
            }
            ctxp[slab][d] = (a0 + a1) + (a2 + a3);
        }
        __syncthreads();
        // ---- H: out = W2@ctx + b2 (folds slab combine); 64 rows x 16 threads ----
        {
            int o = tid >> 4, part = tid & 15;
            float4 c0 = make_float4(0.f, 0.f, 0.f, 0.f);
            float4 c1 = make_float4(0.f, 0.f, 0.f, 0.f);
#pragma unroll
            for (int s2 = 0; s2 < 8; ++s2) {
                const float4* cp = (const float4*)(&ctxp[s2][part * 8]);
                float4 u0 = cp[0], u1 = cp[1];
                c0.x += u0.x; c0.y += u0.y; c0.z += u0.z; c0.w += u0.w;
                c1.x += u1.x; c1.y += u1.y; c1.z += u1.z; c1.w += u1.w;
            }
            const float4* wv = (const float4*)(W2 + (size_t)o * Hn + part * 8);
            float acc = fma4(wv[0], c0, 0.f);
            acc = fma4(wv[1], c1, acc);
            acc += __shfl_xor(acc, 1);
            acc += __shfl_xor(acc, 2);
            acc += __shfl_xor(acc, 4);
            acc += __shfl_xor(acc, 8);
            if (part == 0) {
                float v = acc + b2_s[o];
                tok_s[o] = v;
                dec_out[((size_t)b * Ln + t) * D0n + o] = v;
            }
        }
        __syncthreads();
    }
}

extern "C" void kernel_launch(void* const* d_in, const int* in_sizes, int n_in,
                              void* d_out, int out_size, void* d_ws, size_t ws_size,
                              hipStream_t stream) {
    const float* inputs     = (const float*)d_in[0];
    // d_in[1] = input_lens (int64) — unused by the forward pass
    const float* in_mask    = (const float*)d_in[2];
    const float* enc_lin1_W = (const float*)d_in[3];
    const float* enc_lin1_b = (const float*)d_in[4];
    const float* enc_Wih_f  = (const float*)d_in[5];
    const float* enc_Whh_f  = (const float*)d_in[6];
    const float* enc_b_f    = (const float*)d_in[7];
    const float* enc_Wih_b  = (const float*)d_in[8];
    const float* enc_Whh_b  = (const float*)d_in[9];
    const float* enc_b_b    = (const float*)d_in[10];
    const float* enc_lin2_W = (const float*)d_in[11];
    const float* enc_lin2_b = (const float*)d_in[12];
    const float* vq_emb     = (const float*)d_in[13];
    const float* dec_lin1_W = (const float*)d_in[14];
    const float* dec_lin1_b = (const float*)d_in[15];
    const float* dec_Wih    = (const float*)d_in[16];
    const float* dec_Whh    = (const float*)d_in[17];
    const float* dec_b      = (const float*)d_in[18];
    const float* attn_Wq    = (const float*)d_in[19];
    const float* attn_bq    = (const float*)d_in[20];
    const float* attn_Wk    = (const float*)d_in[21];
    const float* attn_bk    = (const float*)d_in[22];
    const float* attn_Wv    = (const float*)d_in[23];
    const float* attn_bv    = (const float*)d_in[24];
    const float* dec_lin2_W = (const float*)d_in[25];
    const float* dec_lin2_b = (const float*)d_in[26];

    float* out     = (float*)d_out;
    float* dec_out = out;                       // 16*256*64   = 262144
    float* attn_w  = out + 262144;              // 16*256*256  = 1048576
    float* ze      = out + 1310720;             // 16*256*128  = 524288
    float* zq      = out + 1835008;             // 16*256*128  = 524288

    float* ws    = (float*)d_ws;
    float* enc_x = ws;                          // 524288
    float* xWf   = enc_x + 524288;              // 2097152
    float* xWb   = xWf + 2097152;               // 2097152
    float* hf    = xWb + 2097152;               // 524288
    float* hb    = hf + 524288;                 // 524288
    float* kp    = hb + 524288;                 // 524288
    float* vp    = kp + 524288;                 // 524288
    float* c2    = vp + 524288;                 // 512

    // 1. enc_x = relu(inputs @ W1^T + b1)
    k_lin<<<(BLn * Hn + 255) / 256, 256, 0, stream>>>(
        inputs, enc_lin1_W, enc_lin1_b, enc_x, BLn, D0n, Hn, 1);
    // 2. hoisted x @ Wih^T + b for both directions (no h-dependency)
    k_lin<<<(BLn * H4n + 255) / 256, 256, 0, stream>>>(
        enc_x, enc_Wih_f, enc_b_f, xWf, BLn, Hn, H4n, 0);
    k_lin<<<(BLn * H4n + 255) / 256, 256, 0, stream>>>(
        enc_x, enc_Wih_b, enc_b_b, xWb, BLn, Hn, H4n, 0);
    // 3. BiLSTM sequential scans (fwd + bwd concurrently, 32 blocks)
    k_lstm_scan<<<32, 1024, 0, stream>>>(xWf, xWb, enc_Whh_f, enc_Whh_b, hf, hb);
    // 4. ze = [hf, hb] @ W2^T + b2
    k_enc_lin2<<<(BLn * Hn + 255) / 256, 256, 0, stream>>>(hf, hb, enc_lin2_W, enc_lin2_b, ze);
    // 5. VQ
    k_codenorm<<<2, 256, 0, stream>>>(vq_emb, c2);
    k_vq<<<BLn, 256, 0, stream>>>(ze, vq_emb, c2, zq);
    // 6. attention K/V projections from dec_in (== zq numerically)
    k_lin<<<(BLn * Hn + 255) / 256, 256, 0, stream>>>(zq, attn_Wk, attn_bk, kp, BLn, Hn, Hn, 0);
    k_lin<<<(BLn * Hn + 255) / 256, 256, 0, stream>>>(zq, attn_Wv, attn_bv, vp, BLn, Hn, Hn, 0);
    // 7. autoregressive decoder
    k_decoder<<<Bn, 1024, 0, stream>>>(kp, vp, in_mask,
                                       dec_lin1_W, dec_lin1_b,
                                       dec_Wih, dec_Whh, dec_b,
                                       attn_Wq, attn_bq,
                                       dec_lin2_W, dec_lin2_b,
                                       dec_out, attn_w);
}

// Round 3
// 4267.036 us; speedup vs baseline: 1.5413x; 1.4856x over previous
//
#include <hip/hip_runtime.h>

#define Bn  16
#define Ln  256
#define D0n 64
#define Hn  128
#define H4n 512
#define Kn  512
#define BLn 4096   // Bn*Ln

__device__ __forceinline__ float sigf(float x) { return 1.0f / (1.0f + expf(-x)); }

__device__ __forceinline__ float fma4(float4 w, float4 x, float acc) {
    acc = fmaf(w.x, x.x, acc);
    acc = fmaf(w.y, x.y, acc);
    acc = fmaf(w.z, x.z, acc);
    acc = fmaf(w.w, x.w, acc);
    return acc;
}

// ILP-4 dot product (n4 must be a multiple of 4)
__device__ __forceinline__ float dotn(const float4* __restrict__ a,
                                      const float4* __restrict__ w, int n4) {
    float a0 = 0.f, a1 = 0.f, a2 = 0.f, a3 = 0.f;
    for (int i = 0; i < n4; i += 4) {
        a0 = fma4(a[i], w[i], a0);
        a1 = fma4(a[i + 1], w[i + 1], a1);
        a2 = fma4(a[i + 2], w[i + 2], a2);
        a3 = fma4(a[i + 3], w[i + 3], a3);
    }
    return (a0 + a1) + (a2 + a3);
}

// -------- generic Linear: Y[r][c] = scale*(X[r].W[c]) + b[c], opt relu --------
__global__ void k_lin(const float* __restrict__ X, const float* __restrict__ W,
                      const float* __restrict__ b, float* __restrict__ Y,
                      int rows, int in_dim, int out_dim, int do_relu, float scale) {
    int idx = blockIdx.x * blockDim.x + threadIdx.x;
    if (idx >= rows * out_dim) return;
    int r = idx / out_dim, c = idx % out_dim;
    const float4* x4 = (const float4*)(X + (size_t)r * in_dim);
    const float4* w4 = (const float4*)(W + (size_t)c * in_dim);
    float acc = scale * dotn(x4, w4, in_dim >> 2);
    if (b) acc += b[c];
    if (do_relu) acc = fmaxf(acc, 0.f);
    Y[idx] = acc;
}

// -------- enc_lin2 with concatenated [hf, hb] input --------
__global__ void k_enc_lin2(const float* __restrict__ hf, const float* __restrict__ hb,
                           const float* __restrict__ W2, const float* __restrict__ b2,
                           float* __restrict__ ze) {
    int idx = blockIdx.x * blockDim.x + threadIdx.x;
    if (idx >= BLn * Hn) return;
    int r = idx / Hn, c = idx % Hn;
    const float* w = W2 + (size_t)c * (2 * Hn);
    float acc = b2[c];
    acc += dotn((const float4*)(hf + (size_t)r * Hn), (const float4*)w, Hn >> 2);
    acc += dotn((const float4*)(hb + (size_t)r * Hn), (const float4*)(w + Hn), Hn >> 2);
    ze[idx] = acc;
}

// -------- small transpose: out[c][r] = in[r][c] --------
__global__ void k_transpose(const float* __restrict__ in, float* __restrict__ out,
                            int R, int C) {
    int idx = blockIdx.x * blockDim.x + threadIdx.x;
    if (idx >= R * C) return;
    int c = idx / R, r = idx % R;
    out[idx] = in[(size_t)r * C + c];
}

// -------- rearrange [512][32] f4 row-major -> f4-major [32][512] --------
__global__ void k_rearr(const float4* __restrict__ in, float4* __restrict__ out) {
    int idx = blockIdx.x * blockDim.x + threadIdx.x;   // 16384
    if (idx >= 16384) return;
    int f = idx >> 9, row = idx & 511;
    out[idx] = in[(size_t)row * 32 + f];
}

// -------- cst[p] = scale*(bq . kp[p]) + (mask[p]==0 ? -1e9 : 0) --------
__global__ void k_cst(const float* __restrict__ kp, const float* __restrict__ bq,
                      const float* __restrict__ mask, float* __restrict__ cst) {
    int p = blockIdx.x * blockDim.x + threadIdx.x;
    if (p >= BLn) return;
    float a = dotn((const float4*)bq, (const float4*)(kp + (size_t)p * Hn), Hn >> 2);
    cst[p] = a * 0.088388347648318447f + (mask[p] == 0.f ? -1e9f : 0.f);
}

// -------- LSTM scan: 1024 thr, 2 threads per gate row, xW prefetched 1 ahead ----
__global__ __launch_bounds__(1024)
void k_lstm_scan(const float* __restrict__ xWf, const float* __restrict__ xWb,
                 const float* __restrict__ Whh_f, const float* __restrict__ Whh_b,
                 float* __restrict__ hf, float* __restrict__ hb) {
    const int b   = blockIdx.x & 15;
    const int rev = blockIdx.x >> 4;
    const int tid = threadIdx.x;          // 0..1023
    const int row  = tid >> 1;            // gate row 0..511
    const int half = tid & 1;             // which 64-elem half of h
    const float* xW  = rev ? xWb : xWf;
    const float* Whh = rev ? Whh_b : Whh_f;
    float*       ho  = rev ? hb  : hf;

    __shared__ __align__(16) float h_s[Hn];
    __shared__ __align__(16) float g_s[H4n];

    float c_reg = 0.f;
    if (tid < Hn) h_s[tid] = 0.f;

    // resident HALF-row of Whh: 16 float4 = 64 VGPR
    float4 w[16];
    {
        const float4* p = (const float4*)(Whh + (size_t)row * Hn + half * 64);
#pragma unroll
        for (int i = 0; i < 16; ++i) w[i] = p[i];
    }
    const int t0 = rev ? (Ln - 1) : 0;
    float xw_v = (half == 0) ? xW[((size_t)b * Ln + t0) * H4n + row] : 0.f;
    __syncthreads();

    for (int s = 0; s < Ln; ++s) {
        const int t = rev ? (Ln - 1 - s) : s;
        // prefetch next step's xW (covered by FMA + cell + barriers)
        float xw_n = 0.f;
        if (half == 0 && s + 1 < Ln) {
            int tn = rev ? (Ln - 2 - s) : (s + 1);
            xw_n = xW[((size_t)b * Ln + tn) * H4n + row];
        }
        const float4* hh = (const float4*)(h_s + half * 64);
        float a0 = 0.f, a1 = 0.f, a2 = 0.f, a3 = 0.f;
#pragma unroll
        for (int i = 0; i < 16; i += 4) {
            a0 = fma4(w[i], hh[i], a0);
            a1 = fma4(w[i + 1], hh[i + 1], a1);
            a2 = fma4(w[i + 2], hh[i + 2], a2);
            a3 = fma4(w[i + 3], hh[i + 3], a3);
        }
        float acc = (a0 + a1) + (a2 + a3);
        acc += __shfl_xor(acc, 1);
        if (half == 0) g_s[row] = acc + xw_v;
        __syncthreads();
        if (tid < Hn) {
            float ig = sigf(g_s[tid]);
            float fg = sigf(g_s[Hn + tid]);
            float gg = tanhf(g_s[2 * Hn + tid]);
            float og = sigf(g_s[3 * Hn + tid]);
            c_reg = fg * c_reg + ig * gg;
            float hv = og * tanhf(c_reg);
            h_s[tid] = hv;
            ho[((size_t)b * Ln + t) * Hn + tid] = hv;
        }
        __syncthreads();
        xw_v = xw_n;
    }
}

// -------- codebook squared norms --------
__global__ void k_codenorm(const float* __restrict__ emb, float* __restrict__ c2) {
    int k = blockIdx.x * blockDim.x + threadIdx.x;
    if (k >= Kn) return;
    const float4* e4 = (const float4*)(emb + (size_t)k * Hn);
    float acc = 0.f;
    for (int i = 0; i < Hn / 4; ++i) {
        float4 v = e4[i];
        acc = fmaf(v.x, v.x, acc); acc = fmaf(v.y, v.y, acc);
        acc = fmaf(v.z, v.z, acc); acc = fmaf(v.w, v.w, acc);
    }
    c2[k] = acc;
}

// -------- VQ: argmin_k (||e_k||^2 - 2 ze.e_k), first-index tie-break --------
__global__ __launch_bounds__(256)
void k_vq(const float* __restrict__ ze, const float* __restrict__ emb,
          const float* __restrict__ c2, float* __restrict__ zq) {
    const int p = blockIdx.x;           // b*L + l
    const int tid = threadIdx.x;        // 256
    __shared__ __align__(16) float z_s[Hn];
    __shared__ float vals[256];
    __shared__ int   idxs[256];
    if (tid < Hn) z_s[tid] = ze[(size_t)p * Hn + tid];
    __syncthreads();

    float best = 3.0e38f; int bidx = 0;
    for (int k = tid; k < Kn; k += 256) {
        float d = c2[k] - 2.f * dotn((const float4*)z_s,
                                     (const float4*)(emb + (size_t)k * Hn), Hn >> 2);
        if (d < best) { best = d; bidx = k; }   // strict <  => first occurrence
    }
    vals[tid] = best; idxs[tid] = bidx;
    __syncthreads();
    for (int s = 128; s > 0; s >>= 1) {
        if (tid < s) {
            float v2 = vals[tid + s]; int i2 = idxs[tid + s];
            if (v2 < vals[tid] || (v2 == vals[tid] && i2 < idxs[tid])) {
                vals[tid] = v2; idxs[tid] = i2;
            }
        }
        __syncthreads();
    }
    const int nearest = idxs[0];
    if (tid < Hn) zq[(size_t)p * Hn + tid] = emb[(size_t)nearest * Hn + tid];
}

// -------- autoregressive decoder: 16 blocks x 512 thr, register-resident state --
// Serial chain per step: tok -> x -> g -> h -> s(=h.KQ+cst) -> softmax -> out(=attn.VW)
// Whh rows + VW slices persistent in VGPRs; KQ in LDS (XOR-swizzled f4);
// only Wih (rearranged, coalesced) streamed per step with prefetch windows.
__global__ __launch_bounds__(512, 2)
void k_decoder(const float* __restrict__ kq_g, const float* __restrict__ vw_g,
               const float* __restrict__ cst_g,
               const float* __restrict__ W1,   const float* __restrict__ b1_g,
               const float* __restrict__ WihR, const float* __restrict__ WhhR,
               const float* __restrict__ bd_g,
               float* __restrict__ dec_out, float* __restrict__ attn_w) {
    const int b   = blockIdx.x;
    const int tid = threadIdx.x;

    __shared__ __align__(16) float4 kq_lds[Ln * 32];   // 128 KB, swizzled
    __shared__ __align__(16) float tok_s[D0n];
    __shared__ __align__(16) float x_s[Hn];
    __shared__ __align__(16) float h_s[Hn];
    __shared__ __align__(16) float g_s[H4n];
    __shared__ float s_s[Ln];
    __shared__ float attn_sp[8][33];                   // padded: bank = slab+l
    __shared__ float cst_s[Ln];
    __shared__ __align__(16) float b1_s[Hn];
    __shared__ float bd_s[H4n];

    // ---- persistent registers ----
    float4 whr[32];                    // Whh row (f4-major layout, coalesced)
    const float4* WhhR4 = (const float4*)WhhR;
#pragma unroll
    for (int f = 0; f < 32; ++f) whr[f] = WhhR4[f * 512 + tid];

    const int o = tid >> 3, slab = tid & 7;            // phase-GH map
    float vwr[32];                                     // VW'[slab*32+l][o]
#pragma unroll
    for (int l = 0; l < 32; ++l)
        vwr[l] = vw_g[((size_t)b * Ln + slab * 32 + l) * D0n + o];

    // ---- stage KQ into LDS with XOR swizzle (phys f4 = f ^ (l&7)) ----
    const float4* kq4 = (const float4*)(kq_g + (size_t)b * Ln * Hn);
#pragma unroll
    for (int it = 0; it < 16; ++it) {
        int idx = it * 512 + tid;
        int l = idx >> 5, f = idx & 31;
        kq_lds[l * 32 + (f ^ (l & 7))] = kq4[idx];
    }
    if (tid < D0n) tok_s[tid] = 0.f;
    if (tid < Hn)  { h_s[tid] = 0.f; b1_s[tid] = b1_g[tid]; }
    if (tid < Ln)  cst_s[tid] = cst_g[(size_t)b * Ln + tid];
    bd_s[tid] = bd_g[tid];
    float c_reg = 0.f;
    __syncthreads();

    const int arow = tid >> 2, apart = tid & 3;        // phase-A map
    const int el = tid >> 1, ep = tid & 1;             // phase-E map
    const float4* WihR4 = (const float4*)WihR;
    const float4* W1_4  = (const float4*)W1;

    for (int t = 0; t < Ln; ++t) {
        // opaque zero: stop LICM from hoisting loop-invariant weight loads
        int tz = 0;
        asm volatile("" : "+v"(tz));

        // issue W1 slice + first Wih window (latency covered by whh.h below)
        float4 w1r[4];
#pragma unroll
        for (int f = 0; f < 4; ++f) w1r[f] = W1_4[arow * 16 + apart * 4 + f + tz];
        float4 wb0[8], wb1[8];
#pragma unroll
        for (int k = 0; k < 8; ++k) wb0[k] = WihR4[k * 512 + tid + tz];

        // ---- early: accB = bd + Whh . h(t-1)  (registers x LDS broadcast) ----
        float accB = bd_s[tid];
        {
            const float4* h4 = (const float4*)h_s;
#pragma unroll
            for (int f = 0; f < 32; ++f) accB = fma4(whr[f], h4[f], accB);
        }
        // ---- A: x = relu(W1 @ tok + b1); 128 rows x 4 parts ----
        {
            const float4* t4 = (const float4*)tok_s;
            float a = 0.f;
#pragma unroll
            for (int f = 0; f < 4; ++f) a = fma4(w1r[f], t4[apart * 4 + f], a);
            a += __shfl_xor(a, 1);
            a += __shfl_xor(a, 2);
            if (apart == 0) x_s[arow] = fmaxf(a + b1_s[arow], 0.f);
        }
        __syncthreads();
        // ---- B: accB += Wih . x ; streamed windows, 1 thread per gate row ----
        {
            const float4* x4 = (const float4*)x_s;
#pragma unroll
            for (int k = 0; k < 8; ++k) wb1[k] = WihR4[(8 + k) * 512 + tid + tz];
#pragma unroll
            for (int k = 0; k < 8; ++k) accB = fma4(wb0[k], x4[k], accB);
#pragma unroll
            for (int k = 0; k < 8; ++k) wb0[k] = WihR4[(16 + k) * 512 + tid + tz];
#pragma unroll
            for (int k = 0; k < 8; ++k) accB = fma4(wb1[k], x4[8 + k], accB);
#pragma unroll
            for (int k = 0; k < 8; ++k) wb1[k] = WihR4[(24 + k) * 512 + tid + tz];
#pragma unroll
            for (int k = 0; k < 8; ++k) accB = fma4(wb0[k], x4[16 + k], accB);
#pragma unroll
            for (int k = 0; k < 8; ++k) accB = fma4(wb1[k], x4[24 + k], accB);
            g_s[tid] = accB;
        }
        __syncthreads();
        // ---- C: LSTM cell (threads 0..127) ----
        if (tid < Hn) {
            float ig = sigf(g_s[tid]);
            float fg = sigf(g_s[Hn + tid]);
            float gg = tanhf(g_s[2 * Hn + tid]);
            float og = sigf(g_s[3 * Hn + tid]);
            c_reg = fg * c_reg + ig * gg;
            h_s[tid] = og * tanhf(c_reg);
        }
        __syncthreads();
        // ---- E: s[l] = h . KQ[l] + cst[l]; 256 l x 2 parts, swizzled LDS ----
        {
            const float4* h4 = (const float4*)h_s;
            float a = 0.f;
#pragma unroll
            for (int i = 0; i < 16; ++i) {
                int f = ep * 16 + i;
                float4 kv = kq_lds[el * 32 + (f ^ (el & 7))];
                a = fma4(kv, h4[f], a);
            }
            a += __shfl_xor(a, 1);
            if (ep == 0) s_s[el] = a + cst_s[el];
        }
        __syncthreads();
        // ---- F: softmax, wave 0 only ----
        if (tid < 64) {
            float v0 = s_s[tid],       v1 = s_s[tid + 64];
            float v2 = s_s[tid + 128], v3 = s_s[tid + 192];
            float m = fmaxf(fmaxf(v0, v1), fmaxf(v2, v3));
#pragma unroll
            for (int o2 = 32; o2 > 0; o2 >>= 1) m = fmaxf(m, __shfl_xor(m, o2));
            float e0 = expf(v0 - m), e1 = expf(v1 - m);
            float e2 = expf(v2 - m), e3 = expf(v3 - m);
            float s = (e0 + e1) + (e2 + e3);
#pragma unroll
            for (int o2 = 32; o2 > 0; o2 >>= 1) s += __shfl_xor(s, o2);
            float inv = 1.f / s;
            e0 *= inv; e1 *= inv; e2 *= inv; e3 *= inv;
            attn_sp[tid >> 5][tid & 31] = e0;
            attn_sp[(tid + 64) >> 5][tid & 31] = e1;
            attn_sp[(tid + 128) >> 5][tid & 31] = e2;
            attn_sp[(tid + 192) >> 5][tid & 31] = e3;
            float* aw = attn_w + ((size_t)b * Ln + t) * Ln;
            aw[tid] = e0; aw[tid + 64] = e1;
            aw[tid + 128] = e2; aw[tid + 192] = e3;
        }
        __syncthreads();
        // ---- GH: out[o] = sum_l attn[l]*VW'[l][o]; 64 o x 8 slabs ----
        {
            float a = 0.f;
            const float* as = attn_sp[slab];
#pragma unroll
            for (int l = 0; l < 32; ++l) a = fmaf(as[l], vwr[l], a);
            a += __shfl_xor(a, 1);
            a += __shfl_xor(a, 2);
            a += __shfl_xor(a, 4);
            if (slab == 0) {
                tok_s[o] = a;
                dec_out[((size_t)b * Ln + t) * D0n + o] = a;
            }
        }
        __syncthreads();
    }
}

extern "C" void kernel_launch(void* const* d_in, const int* in_sizes, int n_in,
                              void* d_out, int out_size, void* d_ws, size_t ws_size,
                              hipStream_t stream) {
    const float* inputs     = (const float*)d_in[0];
    const float* in_mask    = (const float*)d_in[2];
    const float* enc_lin1_W = (const float*)d_in[3];
    const float* enc_lin1_b = (const float*)d_in[4];
    const float* enc_Wih_f  = (const float*)d_in[5];
    const float* enc_Whh_f  = (const float*)d_in[6];
    const float* enc_b_f    = (const float*)d_in[7];
    const float* enc_Wih_b  = (const float*)d_in[8];
    const float* enc_Whh_b  = (const float*)d_in[9];
    const float* enc_b_b    = (const float*)d_in[10];
    const float* enc_lin2_W = (const float*)d_in[11];
    const float* enc_lin2_b = (const float*)d_in[12];
    const float* vq_emb     = (const float*)d_in[13];
    const float* dec_lin1_W = (const float*)d_in[14];
    const float* dec_lin1_b = (const float*)d_in[15];
    const float* dec_Wih    = (const float*)d_in[16];
    const float* dec_Whh    = (const float*)d_in[17];
    const float* dec_b      = (const float*)d_in[18];
    const float* attn_Wq    = (const float*)d_in[19];
    const float* attn_bq    = (const float*)d_in[20];
    const float* attn_Wk    = (const float*)d_in[21];
    const float* attn_bk    = (const float*)d_in[22];
    const float* attn_Wv    = (const float*)d_in[23];
    const float* attn_bv    = (const float*)d_in[24];
    const float* dec_lin2_W = (const float*)d_in[25];
    const float* dec_lin2_b = (const float*)d_in[26];

    float* out     = (float*)d_out;
    float* dec_out = out;                       // 16*256*64   = 262144
    float* attn_w  = out + 262144;              // 16*256*256  = 1048576
    float* ze      = out + 1310720;             // 16*256*128  = 524288
    float* zq      = out + 1835008;             // 16*256*128  = 524288

    float* ws    = (float*)d_ws;
    float* enc_x = ws;                          // 524288
    float* xWf   = enc_x + 524288;              // 2097152
    float* xWb   = xWf + 2097152;               // 2097152
    float* hf    = xWb + 2097152;               // 524288
    float* hb    = hf + 524288;                 // 524288
    float* kp    = hb + 524288;                 // 524288
    float* vp    = kp + 524288;                 // 524288
    float* c2    = vp + 524288;                 // 512
    // aliases into dead regions:
    float* kq    = xWf;                         // 524288  (xWf dead post-LSTM)
    float* vw    = xWb;                         // 262144  (xWb dead post-LSTM)
    float* cst   = xWb + 262144;                // 4096
    float* WqT   = hf;                          // 16384   (hf dead post-enc_lin2)
    float* WhhR  = hf + 16384;                  // 65536
    float* WihR  = hf + 16384 + 65536;          // 65536

    // ---- encoder ----
    k_lin<<<(BLn * Hn + 255) / 256, 256, 0, stream>>>(
        inputs, enc_lin1_W, enc_lin1_b, enc_x, BLn, D0n, Hn, 1, 1.f);
    k_lin<<<(BLn * H4n + 255) / 256, 256, 0, stream>>>(
        enc_x, enc_Wih_f, enc_b_f, xWf, BLn, Hn, H4n, 0, 1.f);
    k_lin<<<(BLn * H4n + 255) / 256, 256, 0, stream>>>(
        enc_x, enc_Wih_b, enc_b_b, xWb, BLn, Hn, H4n, 0, 1.f);
    k_lstm_scan<<<32, 1024, 0, stream>>>(xWf, xWb, enc_Whh_f, enc_Whh_b, hf, hb);
    k_enc_lin2<<<(BLn * Hn + 255) / 256, 256, 0, stream>>>(hf, hb, enc_lin2_W, enc_lin2_b, ze);
    // ---- weight rearrangements (into hf region, dead now) ----
    k_transpose<<<64, 256, 0, stream>>>(attn_Wq, WqT, Hn, Hn);
    k_rearr<<<64, 256, 0, stream>>>((const float4*)dec_Whh, (float4*)WhhR);
    k_rearr<<<64, 256, 0, stream>>>((const float4*)dec_Wih, (float4*)WihR);
    // ---- VQ ----
    k_codenorm<<<2, 256, 0, stream>>>(vq_emb, c2);
    k_vq<<<BLn, 256, 0, stream>>>(ze, vq_emb, c2, zq);
    // ---- attention precomputes (dec_in == zq) ----
    k_lin<<<(BLn * Hn + 255) / 256, 256, 0, stream>>>(zq, attn_Wk, attn_bk, kp, BLn, Hn, Hn, 0, 1.f);
    k_lin<<<(BLn * Hn + 255) / 256, 256, 0, stream>>>(zq, attn_Wv, attn_bv, vp, BLn, Hn, Hn, 0, 1.f);
    k_lin<<<(BLn * Hn + 255) / 256, 256, 0, stream>>>(
        kp, WqT, nullptr, kq, BLn, Hn, Hn, 0, 0.088388347648318447f);   // KQ = scale*Wq^T.kp
    k_lin<<<(BLn * D0n + 255) / 256, 256, 0, stream>>>(
        vp, dec_lin2_W, dec_lin2_b, vw, BLn, Hn, D0n, 0, 1.f);          // VW' = W2.vp + b2
    k_cst<<<Bn, 256, 0, stream>>>(kp, attn_bq, in_mask, cst);
    // ---- decoder ----
    k_decoder<<<Bn, 512, 0, stream>>>(kq, vw, cst,
                                      dec_lin1_W, dec_lin1_b,
                                      WihR, WhhR, dec_b,
                                      dec_out, attn_w);
}